// Round 20
// baseline (21.719 us; speedup 1.0000x reference)
//
#include <hip/hip_runtime.h>

// GrowingSignature: truncated iterated-sums signature, levels 1..4, F=4.
// x: (32, 512, 4) f32;  out: (32, 512, 341) f32.
// R20 = R19 body + ONE change: the scan stores rows to an LDS staging
// buffer (ds_write, conflict-free, ~100x lower ack latency than HBM NT
// stores) and a post-loop bulk copy streams the block's CONTIGUOUS 43.6 KB
// output span to global with independent pipelined stores. Removes the
// per-batch vmcnt store-drain from the serial scan chain (R17 proved this
// hazard: +0.8us from 4x amortization; this removes it entirely).
// LDS: L-rows (dead after combine) and out-staging TIME-SHARE one buffer.
// Word layout (signatory order): len1 cols 1..4, len2 cols 5..20,
// len3 cols 21..84, len4 cols 85..340; word (a,b,c,e) -> 85+64a+16b+4c+e.

#define SIG_B 32
#define SIG_L 512
#define SIG_NSTEP 511
#define SIG_ROW 341
#define SIG_CS 32            // chunk size (increments)
#define SIG_C 16             // chunks per batch
#define SIG_PAD 344          // workspace row stride (floats, %4==0)
#define SIG_SH 10912         // union: max(15*344=5160, 32*341=10912)

// ---------- Kernel A: local chunk signatures (unchanged) ----------
__global__ __launch_bounds__(256) void sigA(const float* __restrict__ x,
                                            float* __restrict__ Lsig) {
    const int bc = blockIdx.x;
    const int b = bc / SIG_C, c = bc % SIG_C;
    const int tid = threadIdx.x;
    const int t0 = c * SIG_CS;
    const int nt = min(SIG_CS, SIG_NSTEP - t0);   // 32, or 31 for last chunk

    __shared__ float dlds[SIG_CS * 4];
    const float* xb = x + ((size_t)b * SIG_L + t0) * 4;
    if (tid < nt) {
        float4 x0 = *(const float4*)(xb + tid * 4);
        float4 x1 = *(const float4*)(xb + (tid + 1) * 4);
        *(float4*)(dlds + tid * 4) =
            make_float4(x1.x - x0.x, x1.y - x0.y, x1.z - x0.z, x1.w - x0.w);
    }
    __syncthreads();

    const int a = tid >> 6, bb = (tid >> 4) & 3, cc = (tid >> 2) & 3, ee = tid & 3;
    float s1 = 0.f, s2 = 0.f, s3 = 0.f, s4 = 0.f;
    const float* dp = dlds;
    for (int t = 0; t < nt; ++t) {
        const float da = dp[a], db = dp[bb], dc = dp[cc], de = dp[ee];
        dp += 4;
        s4 = fmaf(s3, de, s4);  // top level first: consumes pre-update s3
        s3 = fmaf(s2, dc, s3);
        s2 = fmaf(s1, db, s2);
        s1 += da;
    }
    float* Lr = Lsig + (size_t)bc * SIG_PAD;
    if ((tid & 63) == 0) Lr[1 + a] = s1;
    if ((tid & 15) == 0) Lr[5 + (tid >> 4)] = s2;
    if ((tid & 3) == 0)  Lr[21 + (tid >> 2)] = s3;
    Lr[85 + tid] = s4;
}

// ---------- Kernel C: combine + LDS-staged scan + bulk copy-out ----------
__global__ __launch_bounds__(256) void sigC(const float* __restrict__ x,
                                            const float* __restrict__ Lsig,
                                            float* __restrict__ out) {
    const int bc = blockIdx.x;
    const int b = bc / SIG_C, c = bc % SIG_C;
    const int tid = threadIdx.x;
    const int t0 = c * SIG_CS;
    const int nt = min(SIG_CS, SIG_NSTEP - t0);

    __shared__ float dlds[SIG_CS * 4];
    __shared__ float sh[SIG_SH];   // L rows during combine; out rows during scan

    const float* xb = x + ((size_t)b * SIG_L + t0) * 4;
    if (tid < SIG_CS) {
        float4 d = make_float4(0.f, 0.f, 0.f, 0.f);   // zero-pad tail step
        if (tid < nt) {
            float4 x0 = *(const float4*)(xb + tid * 4);
            float4 x1 = *(const float4*)(xb + (tid + 1) * 4);
            d = make_float4(x1.x - x0.x, x1.y - x0.y, x1.z - x0.z, x1.w - x0.w);
        }
        *(float4*)(dlds + tid * 4) = d;
    }
    // Stage 15 predecessor rows; zero-fill rows j>=c (Chen identity) so the
    // combine is constant-trip (R19: neutral, kept for the unroll).
    {
        const float4* Lb4 = (const float4*)(Lsig + (size_t)b * SIG_C * SIG_PAD);
        float4* L4p = (float4*)sh;
        const int nzero = c * (SIG_PAD / 4);
        const int n4 = (SIG_C - 1) * (SIG_PAD / 4);
        for (int i = tid; i < n4; i += 256) {
            float4 v = Lb4[i];
            if (i >= nzero) v = make_float4(0.f, 0.f, 0.f, 0.f);
            L4p[i] = v;
        }
    }
    __syncthreads();

    const int a = tid >> 6, bb = (tid >> 4) & 3, cc = (tid >> 2) & 3, ee = tid & 3;

    // Chen-combine 15 rows (tail rows zero = identity) -> prefix p1..p4.
    float p1 = 0.f, p2 = 0.f, p3 = 0.f, p4 = 0.f;
#pragma unroll
    for (int j = 0; j < SIG_C - 1; ++j) {
        const float* Lc = sh + j * SIG_PAD;
        const float l1a = Lc[1 + a], l1b = Lc[1 + bb], l1c = Lc[1 + cc], l1e = Lc[1 + ee];
        const float l2ab = Lc[5 + 4 * a + bb], l2bc = Lc[5 + 4 * bb + cc],
                    l2ce = Lc[5 + 4 * cc + ee];
        const float l3abc = Lc[21 + 16 * a + 4 * bb + cc],
                    l3bce = Lc[21 + 16 * bb + 4 * cc + ee];
        const float l4 = Lc[85 + tid];
        p4 += p3 * l1e + p2 * l2ce + p1 * l3bce + l4;  // uses pre-update p1..p3
        p3 += p2 * l1c + p1 * l2bc + l3abc;
        p2 += p1 * l1b + l2ab;
        p1 += l1a;
    }
    __syncthreads();   // all waves done reading L -> sh becomes out staging

    if (c == 0) {  // row 0: [1, zeros] (direct; outside the hot loop)
        float* r0 = out + (size_t)b * SIG_L * SIG_ROW;
        if (tid == 0)        __builtin_nontemporal_store(1.0f, r0 + 0);
        if ((tid & 63) == 0) __builtin_nontemporal_store(0.f, r0 + 1 + a);
        if ((tid & 15) == 0) __builtin_nontemporal_store(0.f, r0 + 5 + (tid >> 4));
        if ((tid & 3) == 0)  __builtin_nontemporal_store(0.f, r0 + 21 + (tid >> 2));
        __builtin_nontemporal_store(0.f, r0 + 85 + tid);
    }

    // Scan: R17's 4-step snapshot batching, but rows go to LDS (ds_write,
    // conflict-free per row: base+tid) instead of global NT stores — no
    // vmcnt store-drain ever touches the serial chain.
    for (int tb = 0; tb < SIG_CS; tb += 4) {
        float o1_0, o2_0, o3_0, o4_0, o1_1, o2_1, o3_1, o4_1;
        float o1_2, o2_2, o3_2, o4_2, o1_3, o2_3, o3_3, o4_3;
#define SIG_STEP_SNAP(U, O1, O2, O3, O4)                                     \
        do {                                                                 \
            const float* dp_ = dlds + (tb + (U)) * 4;                        \
            const float da_ = dp_[a], db_ = dp_[bb],                         \
                        dc_ = dp_[cc], de_ = dp_[ee];                        \
            p4 = fmaf(p3, de_, p4);  /* pre-update lower levels */           \
            p3 = fmaf(p2, dc_, p3);                                          \
            p2 = fmaf(p1, db_, p2);                                          \
            p1 += da_;                                                       \
            O1 = p1; O2 = p2; O3 = p3; O4 = p4;                              \
        } while (0)
        SIG_STEP_SNAP(0, o1_0, o2_0, o3_0, o4_0);
        SIG_STEP_SNAP(1, o1_1, o2_1, o3_1, o4_1);
        SIG_STEP_SNAP(2, o1_2, o2_2, o3_2, o4_2);
        SIG_STEP_SNAP(3, o1_3, o2_3, o3_3, o4_3);
#undef SIG_STEP_SNAP

#define SIG_LDS_ROW(U, O1, O2, O3, O4)                                       \
        do {                                                                 \
            float* r_ = sh + (tb + (U)) * SIG_ROW;                           \
            if (tid == 0)        r_[0] = 1.0f;                               \
            if ((tid & 63) == 0) r_[1 + a] = O1;                             \
            if ((tid & 15) == 0) r_[5 + (tid >> 4)] = O2;                    \
            if ((tid & 3) == 0)  r_[21 + (tid >> 2)] = O3;                   \
            r_[85 + tid] = O4;                                               \
        } while (0)
        SIG_LDS_ROW(0, o1_0, o2_0, o3_0, o4_0);
        SIG_LDS_ROW(1, o1_1, o2_1, o3_1, o4_1);
        SIG_LDS_ROW(2, o1_2, o2_2, o3_2, o4_2);
        SIG_LDS_ROW(3, o1_3, o2_3, o3_3, o4_3);
#undef SIG_LDS_ROW
    }
    __syncthreads();

    // Bulk copy-out: the block's nt rows are one CONTIGUOUS global span.
    // Independent coalesced dword NT stores, fully pipelined across waves.
    {
        float* gout = out + ((size_t)b * SIG_L + (t0 + 1)) * SIG_ROW;
        const int n = nt * SIG_ROW;
        for (int i = tid; i < n; i += 256)
            __builtin_nontemporal_store(sh[i], gout + i);
    }
}

extern "C" void kernel_launch(void* const* d_in, const int* in_sizes, int n_in,
                              void* d_out, int out_size, void* d_ws, size_t ws_size,
                              hipStream_t stream) {
    const float* x = (const float*)d_in[0];   // (32, 512, 4) f32
    float* out = (float*)d_out;               // (32, 512, 341) f32
    float* Lsig = (float*)d_ws;               // 512 * 344 floats

    sigA<<<SIG_B * SIG_C, 256, 0, stream>>>(x, Lsig);
    sigC<<<SIG_B * SIG_C, 256, 0, stream>>>(x, Lsig, out);
}

// Round 21
// 20.701 us; speedup vs baseline: 1.0492x; 1.0492x over previous
//
#include <hip/hip_runtime.h>

// GrowingSignature: truncated iterated-sums signature, levels 1..4, F=4.
// x: (32, 512, 4) f32;  out: (32, 512, 341) f32.
// R21 = R19 sigC (champion, untouched) + wave-time-split sigA: each wave
// scans an 8-step window keeping 4 words/lane (a=0..3 unrolled chains),
// stages its window sub-signature to LDS, wave 0 Chen-combines the 4 rows.
// Serial depth 32 -> ~12 slots at the measured ~320 cyc/slot.
// Word layout (signatory order): len1 cols 1..4, len2 cols 5..20,
// len3 cols 21..84, len4 cols 85..340; word (a,b,c,e) -> 85+64a+16b+4c+e.

#define SIG_B 32
#define SIG_L 512
#define SIG_NSTEP 511
#define SIG_ROW 341
#define SIG_CS 32            // chunk size (increments)
#define SIG_C 16             // chunks per batch
#define SIG_PAD 344          // workspace row stride (floats, %4==0)
#define SIG_WS 8             // steps per wave window (SIG_CS / 4 waves)

// ---------- Kernel A: wave-time-split chunk signatures ----------
__global__ __launch_bounds__(256) void sigA(const float* __restrict__ x,
                                            float* __restrict__ Lsig) {
    const int bc = blockIdx.x;
    const int b = bc / SIG_C, c = bc % SIG_C;
    const int tid = threadIdx.x;
    const int w = tid >> 6, l = tid & 63;
    const int t0 = c * SIG_CS;
    const int nt = min(SIG_CS, SIG_NSTEP - t0);   // 32, or 31 for c=15

    __shared__ float dlds[SIG_CS * 4];
    __shared__ float S[4 * SIG_PAD];              // 4 window sub-signatures

    const float* xb = x + ((size_t)b * SIG_L + t0) * 4;
    if (tid < SIG_CS) {
        float4 d = make_float4(0.f, 0.f, 0.f, 0.f);   // zero-pad tail step
        if (tid < nt) {
            float4 x0 = *(const float4*)(xb + tid * 4);
            float4 x1 = *(const float4*)(xb + (tid + 1) * 4);
            d = make_float4(x1.x - x0.x, x1.y - x0.y, x1.z - x0.z, x1.w - x0.w);
        }
        *(float4*)(dlds + tid * 4) = d;
    }
    __syncthreads();

    const int b2 = (l >> 4) & 3, cc = (l >> 2) & 3, ee = l & 3;

    // 4 words per lane: (a, b2, cc, ee) for a = 0..3. Zero increments extend
    // by the identity, so padded steps are harmless.
    float s1_0 = 0.f, s2_0 = 0.f, s3_0 = 0.f, s4_0 = 0.f;
    float s1_1 = 0.f, s2_1 = 0.f, s3_1 = 0.f, s4_1 = 0.f;
    float s1_2 = 0.f, s2_2 = 0.f, s3_2 = 0.f, s4_2 = 0.f;
    float s1_3 = 0.f, s2_3 = 0.f, s3_3 = 0.f, s4_3 = 0.f;

    const float* dp = dlds + w * SIG_WS * 4;      // this wave's 8-step window
#pragma unroll
    for (int u = 0; u < SIG_WS; ++u) {
        const float d0 = dp[0], d1 = dp[1], d2 = dp[2], d3 = dp[3];
        const float db = dp[b2], dcv = dp[cc], de = dp[ee];  // per-lane LDS reads
        dp += 4;
        // top level first: each update consumes pre-update lower chain
        s4_0 = fmaf(s3_0, de, s4_0); s3_0 = fmaf(s2_0, dcv, s3_0);
        s2_0 = fmaf(s1_0, db, s2_0); s1_0 += d0;
        s4_1 = fmaf(s3_1, de, s4_1); s3_1 = fmaf(s2_1, dcv, s3_1);
        s2_1 = fmaf(s1_1, db, s2_1); s1_1 += d1;
        s4_2 = fmaf(s3_2, de, s4_2); s3_2 = fmaf(s2_2, dcv, s3_2);
        s2_2 = fmaf(s1_2, db, s2_2); s1_2 += d2;
        s4_3 = fmaf(s3_3, de, s4_3); s3_3 = fmaf(s2_3, dcv, s3_3);
        s2_3 = fmaf(s1_3, db, s2_3); s1_3 += d3;
    }

    // Stage this wave's window sub-signature (duty-lane pattern).
    {
        float* Sw = S + w * SIG_PAD;
        if (l == 0) { Sw[1] = s1_0; Sw[2] = s1_1; Sw[3] = s1_2; Sw[4] = s1_3; }
        if ((l & 15) == 0) {            // cc==0 && ee==0; b2 = l>>4
            Sw[5 + b2] = s2_0;  Sw[5 + 4 + b2] = s2_1;
            Sw[5 + 8 + b2] = s2_2; Sw[5 + 12 + b2] = s2_3;
        }
        if ((l & 3) == 0) {             // ee==0; l>>2 = 4*b2+cc
            Sw[21 + (l >> 2)] = s3_0;      Sw[21 + 16 + (l >> 2)] = s3_1;
            Sw[21 + 32 + (l >> 2)] = s3_2; Sw[21 + 48 + (l >> 2)] = s3_3;
        }
        Sw[85 + l] = s4_0;       Sw[85 + 64 + l] = s4_1;
        Sw[85 + 128 + l] = s4_2; Sw[85 + 192 + l] = s4_3;
    }
    __syncthreads();

    // Wave 0: Chen-combine S[0] (x) S[1] (x) S[2] (x) S[3] -> chunk signature.
    if (w == 0) {
        float p1_0 = 0.f, p2_0 = 0.f, p3_0 = 0.f, p4_0 = 0.f;
        float p1_1 = 0.f, p2_1 = 0.f, p3_1 = 0.f, p4_1 = 0.f;
        float p1_2 = 0.f, p2_2 = 0.f, p3_2 = 0.f, p4_2 = 0.f;
        float p1_3 = 0.f, p2_3 = 0.f, p3_3 = 0.f, p4_3 = 0.f;
#pragma unroll
        for (int j = 0; j < 4; ++j) {
            const float* Sc = S + j * SIG_PAD;
            // shared across the lane's 4 words
            const float l1b = Sc[1 + b2], l1c = Sc[1 + cc], l1e = Sc[1 + ee];
            const float l2bc = Sc[5 + 4 * b2 + cc], l2ce = Sc[5 + 4 * cc + ee];
            const float l3bce = Sc[21 + 16 * b2 + 4 * cc + ee];
            // per-a reads
            const float l1a0 = Sc[1], l1a1 = Sc[2], l1a2 = Sc[3], l1a3 = Sc[4];
#define SIG_COMB(A, P1, P2, P3, P4, L1A)                                     \
            do {                                                             \
                const float l2ab = Sc[5 + 4 * (A) + b2];                     \
                const float l3abc = Sc[21 + 16 * (A) + 4 * b2 + cc];         \
                const float l4 = Sc[85 + 64 * (A) + l];                      \
                P4 += P3 * l1e + P2 * l2ce + P1 * l3bce + l4;                \
                P3 += P2 * l1c + P1 * l2bc + l3abc;                          \
                P2 += P1 * l1b + l2ab;                                       \
                P1 += L1A;                                                   \
            } while (0)
            SIG_COMB(0, p1_0, p2_0, p3_0, p4_0, l1a0);
            SIG_COMB(1, p1_1, p2_1, p3_1, p4_1, l1a1);
            SIG_COMB(2, p1_2, p2_2, p3_2, p4_2, l1a2);
            SIG_COMB(3, p1_3, p2_3, p3_3, p4_3, l1a3);
#undef SIG_COMB
        }
        float* Lr = Lsig + (size_t)bc * SIG_PAD;
        if (l == 0) { Lr[1] = p1_0; Lr[2] = p1_1; Lr[3] = p1_2; Lr[4] = p1_3; }
        if ((l & 15) == 0) {
            Lr[5 + b2] = p2_0;  Lr[5 + 4 + b2] = p2_1;
            Lr[5 + 8 + b2] = p2_2; Lr[5 + 12 + b2] = p2_3;
        }
        if ((l & 3) == 0) {
            Lr[21 + (l >> 2)] = p3_0;      Lr[21 + 16 + (l >> 2)] = p3_1;
            Lr[21 + 32 + (l >> 2)] = p3_2; Lr[21 + 48 + (l >> 2)] = p3_3;
        }
        Lr[85 + l] = p4_0;       Lr[85 + 64 + l] = p4_1;
        Lr[85 + 128 + l] = p4_2; Lr[85 + 192 + l] = p4_3;
    }
}

// ---------- Kernel C: R19 champion (unrolled combine + 4-step batching) ----------
__global__ __launch_bounds__(256) void sigC(const float* __restrict__ x,
                                            const float* __restrict__ Lsig,
                                            float* __restrict__ out) {
    const int bc = blockIdx.x;
    const int b = bc / SIG_C, c = bc % SIG_C;
    const int tid = threadIdx.x;
    const int t0 = c * SIG_CS;
    const int nt = min(SIG_CS, SIG_NSTEP - t0);

    __shared__ float dlds[SIG_CS * 4];
    __shared__ float L[(SIG_C - 1) * SIG_PAD];   // 15 rows, rows >= c zeroed

    const float* xb = x + ((size_t)b * SIG_L + t0) * 4;
    if (tid < SIG_CS) {
        float4 d = make_float4(0.f, 0.f, 0.f, 0.f);   // zero-pad tail step
        if (tid < nt) {
            float4 x0 = *(const float4*)(xb + tid * 4);
            float4 x1 = *(const float4*)(xb + (tid + 1) * 4);
            d = make_float4(x1.x - x0.x, x1.y - x0.y, x1.z - x0.z, x1.w - x0.w);
        }
        *(float4*)(dlds + tid * 4) = d;
    }
    {
        const float4* Lb4 = (const float4*)(Lsig + (size_t)b * SIG_C * SIG_PAD);
        float4* L4p = (float4*)L;
        const int nzero = c * (SIG_PAD / 4);
        const int n4 = (SIG_C - 1) * (SIG_PAD / 4);
        for (int i = tid; i < n4; i += 256) {
            float4 v = Lb4[i];
            if (i >= nzero) v = make_float4(0.f, 0.f, 0.f, 0.f);
            L4p[i] = v;
        }
    }
    __syncthreads();

    const int a = tid >> 6, bb = (tid >> 4) & 3, cc = (tid >> 2) & 3, ee = tid & 3;

    float p1 = 0.f, p2 = 0.f, p3 = 0.f, p4 = 0.f;
#pragma unroll
    for (int j = 0; j < SIG_C - 1; ++j) {
        const float* Lc = L + j * SIG_PAD;
        const float l1a = Lc[1 + a], l1b = Lc[1 + bb], l1c = Lc[1 + cc], l1e = Lc[1 + ee];
        const float l2ab = Lc[5 + 4 * a + bb], l2bc = Lc[5 + 4 * bb + cc],
                    l2ce = Lc[5 + 4 * cc + ee];
        const float l3abc = Lc[21 + 16 * a + 4 * bb + cc],
                    l3bce = Lc[21 + 16 * bb + 4 * cc + ee];
        const float l4 = Lc[85 + tid];
        p4 += p3 * l1e + p2 * l2ce + p1 * l3bce + l4;  // uses pre-update p1..p3
        p3 += p2 * l1c + p1 * l2bc + l3abc;
        p2 += p1 * l1b + l2ab;
        p1 += l1a;
    }

    float* row = out + ((size_t)b * SIG_L + (t0 + 1)) * SIG_ROW;

    if (c == 0) {  // row 0: [1, zeros]
        float* r0 = out + (size_t)b * SIG_L * SIG_ROW;
        if (tid == 0)        __builtin_nontemporal_store(1.0f, r0 + 0);
        if ((tid & 63) == 0) __builtin_nontemporal_store(0.f, r0 + 1 + a);
        if ((tid & 15) == 0) __builtin_nontemporal_store(0.f, r0 + 5 + (tid >> 4));
        if ((tid & 3) == 0)  __builtin_nontemporal_store(0.f, r0 + 21 + (tid >> 2));
        __builtin_nontemporal_store(0.f, r0 + 85 + tid);
    }

    for (int tb = 0; tb < SIG_CS; tb += 4) {
        float o1_0, o2_0, o3_0, o4_0, o1_1, o2_1, o3_1, o4_1;
        float o1_2, o2_2, o3_2, o4_2, o1_3, o2_3, o3_3, o4_3;
#define SIG_STEP_SNAP(U, O1, O2, O3, O4)                                     \
        do {                                                                 \
            const float* dp_ = dlds + (tb + (U)) * 4;                        \
            const float da_ = dp_[a], db_ = dp_[bb],                         \
                        dc_ = dp_[cc], de_ = dp_[ee];                        \
            p4 = fmaf(p3, de_, p4);  /* pre-update lower levels */           \
            p3 = fmaf(p2, dc_, p3);                                          \
            p2 = fmaf(p1, db_, p2);                                          \
            p1 += da_;                                                       \
            O1 = p1; O2 = p2; O3 = p3; O4 = p4;                              \
        } while (0)
        SIG_STEP_SNAP(0, o1_0, o2_0, o3_0, o4_0);
        SIG_STEP_SNAP(1, o1_1, o2_1, o3_1, o4_1);
        SIG_STEP_SNAP(2, o1_2, o2_2, o3_2, o4_2);
        SIG_STEP_SNAP(3, o1_3, o2_3, o3_3, o4_3);
#undef SIG_STEP_SNAP

#define SIG_STORE_ROW(U, O1, O2, O3, O4)                                     \
        do {                                                                 \
            if (tb + (U) < nt) {                                             \
                float* r_ = row + (size_t)(tb + (U)) * SIG_ROW;              \
                if (tid == 0)                                                \
                    __builtin_nontemporal_store(1.0f, r_ + 0);               \
                if ((tid & 63) == 0)                                         \
                    __builtin_nontemporal_store(O1, r_ + 1 + a);             \
                if ((tid & 15) == 0)                                         \
                    __builtin_nontemporal_store(O2, r_ + 5 + (tid >> 4));    \
                if ((tid & 3) == 0)                                          \
                    __builtin_nontemporal_store(O3, r_ + 21 + (tid >> 2));   \
                __builtin_nontemporal_store(O4, r_ + 85 + tid);              \
            }                                                                \
        } while (0)
        SIG_STORE_ROW(0, o1_0, o2_0, o3_0, o4_0);
        SIG_STORE_ROW(1, o1_1, o2_1, o3_1, o4_1);
        SIG_STORE_ROW(2, o1_2, o2_2, o3_2, o4_2);
        SIG_STORE_ROW(3, o1_3, o2_3, o3_3, o4_3);
#undef SIG_STORE_ROW
    }
}

extern "C" void kernel_launch(void* const* d_in, const int* in_sizes, int n_in,
                              void* d_out, int out_size, void* d_ws, size_t ws_size,
                              hipStream_t stream) {
    const float* x = (const float*)d_in[0];   // (32, 512, 4) f32
    float* out = (float*)d_out;               // (32, 512, 341) f32
    float* Lsig = (float*)d_ws;               // 512 * 344 floats

    sigA<<<SIG_B * SIG_C, 256, 0, stream>>>(x, Lsig);
    sigC<<<SIG_B * SIG_C, 256, 0, stream>>>(x, Lsig, out);
}